// Round 1
// baseline (236.921 us; speedup 1.0000x reference)
//
#include <hip/hip_runtime.h>
#include <hip/hip_bf16.h>
#include <stdint.h>

// PointNet EdgeConv, 2 layers. Round 16.
// R10: atomic-free bucket sort + MFMA edge_seg.                278 us
// R13: U table packed bf16 (gather 128 -> 64 B).               257 us
// R14: cvt_pk_bf16 + bf16 m-matrix + bias-in-C.                233 us
// R15: fused setup; 512-edge edge_seg blocks.                  230 us <- best
// R16: direct-to-fragment gathers in edge_seg. The A-fragment layout is
//      static: lane (ln,half) needs channels [8h,8h+8) and [16+8h,+8) of
//      edges 64w+ln and 64w+ln+32 -> two uint4 of Ubf + four float4 of V
//      per edge, loaded straight from global. B fragment precomputed into
//      a 2KB per-layer global table by setup. Kills the 40KB ds_write +
//      48KB ds_read staging round-trip and 2 of 3 barriers; LDS 43->33KB.
//      Numerics bit-identical (same cvt2/fmax chain).

#define BS 256
#define EBS 512        // edge_seg block size (512 edges per block)
#define K1_EDGES 4096  // edges staged per block in scatter pass
#define P2_CAP 3072    // max edges per 128-dst range bucket (mean 2048, +22 sigma)

typedef float v2f __attribute__((ext_vector_type(2)));
typedef __attribute__((ext_vector_type(8))) short bf16x8;
typedef __attribute__((ext_vector_type(16))) float f32x16;
typedef __bf16 bf16v2 __attribute__((ext_vector_type(2)));

__device__ __forceinline__ unsigned ordenc(float f) {
    unsigned u = __float_as_uint(f);
    return (u & 0x80000000u) ? ~u : (u | 0x80000000u);
}
__device__ __forceinline__ float orddec(unsigned o) {
    unsigned u = (o & 0x80000000u) ? (o ^ 0x80000000u) : ~o;
    return __uint_as_float(u);
}
#define ORD_NEG_INF 0x007FFFFFu  // ordenc(-inf)

// two f32 -> packed bf16 pair (RNE) via v_cvt_pk_bf16_f32; x -> low half
__device__ __forceinline__ unsigned cvt2(float x, float y) {
    v2f v = {x, y};
    bf16v2 b = __builtin_convertvector(v, bf16v2);
    return __builtin_bit_cast(unsigned, b);
}
__device__ __forceinline__ float bflo(unsigned u) { return __uint_as_float(u << 16); }
__device__ __forceinline__ float bfhi(unsigned u) { return __uint_as_float(u & 0xFFFF0000u); }

// build 8 channels of h = relu(bf16(U) - V) as 4 packed bf16 pairs
__device__ __forceinline__ uint4 mk_frag(uint4 ua, float4 v0, float4 v1) {
    uint4 o;
    o.x = cvt2(fmaxf(bflo(ua.x) - v0.x, 0.0f), fmaxf(bfhi(ua.x) - v0.y, 0.0f));
    o.y = cvt2(fmaxf(bflo(ua.y) - v0.z, 0.0f), fmaxf(bfhi(ua.y) - v0.w, 0.0f));
    o.z = cvt2(fmaxf(bflo(ua.z) - v1.x, 0.0f), fmaxf(bfhi(ua.z) - v1.y, 0.0f));
    o.w = cvt2(fmaxf(bflo(ua.w) - v1.z, 0.0f), fmaxf(bfhi(ua.w) - v1.w, 0.0f));
    return o;
}

// ---------------- fused setup: range-hist | prep1 | agg-init | Wbt pack -----
// Blocks [0, NB1)            : per-block range histogram of dst>>7
// Blocks [NB1, NB1+NBn)      : prep1 (U bf16 / V f32 for layer 1)
// Blocks [NB1+NBn, +gridN32) : init aggA/aggB to ORD_NEG_INF
// Last block                 : pack per-lane B fragments for both layers
__global__ __launch_bounds__(BS) void setup_kernel(
    const int* __restrict__ ei, int E, int NRP, int* __restrict__ blockHist,
    const float* __restrict__ pos, const float* __restrict__ Wa, const float* __restrict__ ba,
    unsigned* __restrict__ Ubf, float* __restrict__ V, int N, unsigned* __restrict__ aggA,
    unsigned* __restrict__ aggB, int n32, int NB1, int NBn, int gridN32,
    const float* __restrict__ Wb2, const float* __restrict__ Wb4,
    unsigned* __restrict__ WbtG) {
    __shared__ int hist[1024];
    const int tid = threadIdx.x;
    const int b = blockIdx.x;
    if (b < NB1) {
        for (int r = tid; r < 1024; r += BS) hist[r] = 0;
        __syncthreads();
        const int base = b * K1_EDGES;
        const int M = min(K1_EDGES, E - base);
        for (int i = tid; i < M; i += BS) atomicAdd(&hist[ei[E + base + i] >> 7], 1);
        __syncthreads();
        for (int r = tid; r < NRP; r += BS) blockHist[b * NRP + r] = hist[r];
    } else if (b < NB1 + NBn) {
        const int n = (b - NB1) * BS + tid;
        if (n >= N) return;
        const float p[3] = {pos[3 * n], pos[3 * n + 1], pos[3 * n + 2]};
        v2f u[16], v[16];
#pragma unroll
        for (int g = 0; g < 16; ++g) {
            u[g] = *reinterpret_cast<const v2f*>(&ba[g * 2]);
            v2f z = {0.0f, 0.0f};
            v[g] = z;
        }
#pragma unroll
        for (int i = 0; i < 3; ++i) {
            const v2f f = {p[i], p[i]};
#pragma unroll
            for (int g = 0; g < 16; ++g) {
                const v2f wA = *reinterpret_cast<const v2f*>(&Wa[i * 32 + g * 2]);
                const v2f wB = *reinterpret_cast<const v2f*>(&Wa[(i + 3) * 32 + g * 2]);
                u[g] = __builtin_elementwise_fma(f, wA + wB, u[g]);
                v[g] = __builtin_elementwise_fma(f, wB, v[g]);
            }
        }
        uint4* Up = reinterpret_cast<uint4*>(Ubf + (size_t)n * 16);
        float4* Vp = reinterpret_cast<float4*>(V + (size_t)n * 32);
#pragma unroll
        for (int q = 0; q < 4; ++q) {
            uint4 o;
            o.x = cvt2(u[4 * q + 0].x, u[4 * q + 0].y);
            o.y = cvt2(u[4 * q + 1].x, u[4 * q + 1].y);
            o.z = cvt2(u[4 * q + 2].x, u[4 * q + 2].y);
            o.w = cvt2(u[4 * q + 3].x, u[4 * q + 3].y);
            Up[q] = o;
        }
#pragma unroll
        for (int q = 0; q < 8; ++q)
            Vp[q] = make_float4(v[2 * q].x, v[2 * q].y, v[2 * q + 1].x, v[2 * q + 1].y);
    } else if (b < NB1 + NBn + gridN32) {
        const int i = (b - NB1 - NBn) * BS + tid;
        if (i < n32) {
            aggA[i] = ORD_NEG_INF;
            aggB[i] = ORD_NEG_INF;
        }
    } else {
        // pack per-lane B fragments (bf16 pairs) for both layers: 2 x 512 dw
        if (tid < 128) {
            const int layer = tid >> 6;
            const int t = tid & 63;
            const int lnp = t & 31;
            const int hp = t >> 5;
            const float* Wb = layer ? Wb4 : Wb2;
            unsigned* dst = WbtG + layer * 512 + t * 8;
#pragma unroll
            for (int q = 0; q < 4; ++q) {
                const int p = 4 * hp + q;
                dst[q] = cvt2(Wb[(2 * p) * 32 + lnp], Wb[(2 * p + 1) * 32 + lnp]);
                dst[4 + q] = cvt2(Wb[(2 * p + 16) * 32 + lnp], Wb[(2 * p + 17) * 32 + lnp]);
            }
        }
    }
}

__global__ __launch_bounds__(BS) void finalize_kernel(unsigned* __restrict__ buf, int n) {
    int i = blockIdx.x * BS + threadIdx.x;
    if (i < n) {
        float v = orddec(buf[i]);
        reinterpret_cast<float*>(buf)[i] = fmaxf(v, 0.0f);
    }
}

// ---------------- pass 2a: per-(block,range) LOCAL prefixes + range totals --
__global__ __launch_bounds__(512) void off_scan_kernel(const int* __restrict__ blockHist,
                                                       int NB1, int NRP,
                                                       int* __restrict__ off,
                                                       int* __restrict__ total) {
    const int r = (blockIdx.x * 512 + threadIdx.x) >> 6;
    const int lane = threadIdx.x & 63;
    if (r >= NRP) return;
    int carry = 0;
    const int chunks = (NB1 + 63) / 64;
    for (int c = 0; c < chunks; ++c) {
        const int b = c * 64 + lane;
        const int v = (b < NB1) ? blockHist[b * NRP + r] : 0;
        int x = v;
#pragma unroll
        for (int d = 1; d < 64; d <<= 1) {
            int y = __shfl_up(x, d, 64);
            if (lane >= d) x += y;
        }
        if (b < NB1) off[b * NRP + r] = carry + (x - v);
        carry += __shfl(x, 63, 64);
    }
    if (lane == 0) total[r] = carry;
}

// ---------------- pass 2b: exclusive scan of totals -> rangeBase ------------
__global__ __launch_bounds__(1024) void range_scan_kernel(const int* __restrict__ total,
                                                          int NRP, int* __restrict__ rangeBase) {
    __shared__ int s[1024];
    const int t = threadIdx.x;
    const int v = (t < NRP) ? total[t] : 0;
    s[t] = v;
    __syncthreads();
    for (int off = 1; off < 1024; off <<= 1) {
        int add = (t >= off) ? s[t - off] : 0;
        __syncthreads();
        s[t] += add;
        __syncthreads();
    }
    if (t < NRP) rangeBase[t] = s[t] - v;
}

// ---------------- pass 1b: LDS-ranked scatter into range buckets ------------
__global__ __launch_bounds__(BS) void bucket_scatter_kernel(
    const int* __restrict__ ei, int E, int NRP, const int* __restrict__ off,
    const int* __restrict__ rangeBase, int2* __restrict__ sedgeB) {
    __shared__ int2 stage[K1_EDGES];          // 32 KB
    __shared__ unsigned short inv[K1_EDGES];  // 8 KB
    __shared__ int hist[1024], start[1024], cursor[1024];
    __shared__ int ts[BS];
    const int tid = threadIdx.x;
    for (int r = tid; r < 1024; r += BS) hist[r] = 0;
    __syncthreads();
    const int base = blockIdx.x * K1_EDGES;
    const int M = min(K1_EDGES, E - base);
    for (int i = tid; i < M; i += BS) {
        const int2 p = make_int2(ei[base + i], ei[E + base + i]);
        stage[i] = p;
        atomicAdd(&hist[p.y >> 7], 1);
    }
    __syncthreads();
    {
        const int i0 = tid * 4;
        const int l0 = hist[i0], l1 = hist[i0 + 1], l2 = hist[i0 + 2], l3 = hist[i0 + 3];
        const int tsum = l0 + l1 + l2 + l3;
        ts[tid] = tsum;
        __syncthreads();
        for (int off2 = 1; off2 < BS; off2 <<= 1) {
            int add = (tid >= off2) ? ts[tid - off2] : 0;
            __syncthreads();
            ts[tid] += add;
            __syncthreads();
        }
        const int texcl = ts[tid] - tsum;
        start[i0] = texcl;
        start[i0 + 1] = texcl + l0;
        start[i0 + 2] = texcl + l0 + l1;
        start[i0 + 3] = texcl + l0 + l1 + l2;
        cursor[i0] = start[i0];
        cursor[i0 + 1] = start[i0 + 1];
        cursor[i0 + 2] = start[i0 + 2];
        cursor[i0 + 3] = start[i0 + 3];
    }
    __syncthreads();
    for (int i = tid; i < M; i += BS) {
        const int pos = atomicAdd(&cursor[stage[i].y >> 7], 1);
        inv[pos] = (unsigned short)i;
    }
    __syncthreads();
    const int* offb = off + blockIdx.x * NRP;
    for (int j = tid; j < M; j += BS) {
        const int2 p = stage[inv[j]];
        const int r = p.y >> 7;
        sedgeB[rangeBase[r] + offb[r] + (j - start[r])] = p;  // contiguous runs
    }
}

// ---------------- pass 3: in-LDS sort within each range bucket --------------
__global__ __launch_bounds__(BS) void bucket_sort_kernel(
    const int2* __restrict__ sedgeB, const int* __restrict__ rangeBase,
    const int* __restrict__ total, int N, int2* __restrict__ sedge, int* __restrict__ row_ptr,
    int* __restrict__ cnt) {
    __shared__ int2 stage[P2_CAP];
    __shared__ unsigned short inv[P2_CAP];
    __shared__ int hist[128], start[128], cursor[128];
    const int r = blockIdx.x;
    const int tid = threadIdx.x;
    const int base = rangeBase[r];
    const int M = total[r];
    const bool fast = (M <= P2_CAP);
    if (tid < 128) hist[tid] = 0;
    __syncthreads();
    if (fast) {
        for (int i = tid; i < M; i += BS) {
            const int2 p = sedgeB[base + i];
            stage[i] = p;
            atomicAdd(&hist[p.y & 127], 1);
        }
    } else {  // statistically never; correct slow path
        if (tid < 128) {
            int c = 0;
            for (int i = 0; i < M; ++i) c += ((sedgeB[base + i].y & 127) == tid);
            hist[tid] = c;
        }
    }
    __syncthreads();
    if (tid < 128) start[tid] = hist[tid];
    __syncthreads();
    for (int off2 = 1; off2 < 128; off2 <<= 1) {
        int add = 0;
        if (tid < 128 && tid >= off2) add = start[tid - off2];
        __syncthreads();
        if (tid < 128) start[tid] += add;
        __syncthreads();
    }
    if (tid < 128) {
        const int excl = start[tid] - hist[tid];
        start[tid] = excl;
        cursor[tid] = excl;
        const int node = r * 128 + tid;
        if (node < N) {
            row_ptr[node] = base + excl;
            cnt[node] = hist[tid];
        }
    }
    __syncthreads();
    if (fast) {
        for (int i = tid; i < M; i += BS) {
            const int pos = atomicAdd(&cursor[stage[i].y & 127], 1);
            inv[pos] = (unsigned short)i;
        }
        __syncthreads();
        for (int j = tid; j < M; j += BS) sedge[base + j] = stage[inv[j]];
    } else {
        if (tid < 128) {
            int c = base + start[tid];
            for (int i = 0; i < M; ++i) {
                const int2 p = sedgeB[base + i];
                if ((p.y & 127) == tid) sedge[c++] = p;
            }
        }
    }
}

// Layer 2 prep: reads layer-1 agg (ordered uint), decodes h inline.
__global__ __launch_bounds__(BS) void prep2_kernel(const float* __restrict__ pos,
                                                   const unsigned* __restrict__ aggA,
                                                   const float* __restrict__ Wa,
                                                   const float* __restrict__ ba,
                                                   unsigned* __restrict__ Ubf,
                                                   float* __restrict__ V, int N) {
    int n = blockIdx.x * BS + threadIdx.x;
    if (n >= N) return;
    float h[32];
    const uint4* hp = reinterpret_cast<const uint4*>(aggA + (size_t)n * 32);
#pragma unroll
    for (int q = 0; q < 8; ++q) {
        uint4 t = hp[q];
        h[4 * q + 0] = fmaxf(orddec(t.x), 0.0f);
        h[4 * q + 1] = fmaxf(orddec(t.y), 0.0f);
        h[4 * q + 2] = fmaxf(orddec(t.z), 0.0f);
        h[4 * q + 3] = fmaxf(orddec(t.w), 0.0f);
    }
    const float p[3] = {pos[3 * n], pos[3 * n + 1], pos[3 * n + 2]};
    v2f u[16], v[16];
#pragma unroll
    for (int g = 0; g < 16; ++g) {
        u[g] = *reinterpret_cast<const v2f*>(&ba[g * 2]);
        v2f z = {0.0f, 0.0f};
        v[g] = z;
    }
#pragma unroll
    for (int i = 0; i < 32; ++i) {
        const v2f f = {h[i], h[i]};
#pragma unroll
        for (int g = 0; g < 16; ++g) {
            const v2f w = *reinterpret_cast<const v2f*>(&Wa[i * 32 + g * 2]);
            u[g] = __builtin_elementwise_fma(f, w, u[g]);
        }
    }
#pragma unroll
    for (int i = 0; i < 3; ++i) {
        const v2f f = {p[i], p[i]};
#pragma unroll
        for (int g = 0; g < 16; ++g) {
            const v2f w = *reinterpret_cast<const v2f*>(&Wa[(32 + i) * 32 + g * 2]);
            u[g] = __builtin_elementwise_fma(f, w, u[g]);
            v[g] = __builtin_elementwise_fma(f, w, v[g]);
        }
    }
    uint4* Up = reinterpret_cast<uint4*>(Ubf + (size_t)n * 16);
    float4* Vp = reinterpret_cast<float4*>(V + (size_t)n * 32);
#pragma unroll
    for (int q = 0; q < 4; ++q) {
        uint4 o;
        o.x = cvt2(u[4 * q + 0].x, u[4 * q + 0].y);
        o.y = cvt2(u[4 * q + 1].x, u[4 * q + 1].y);
        o.z = cvt2(u[4 * q + 2].x, u[4 * q + 2].y);
        o.w = cvt2(u[4 * q + 3].x, u[4 * q + 3].y);
        Up[q] = o;
    }
#pragma unroll
    for (int q = 0; q < 8; ++q)
        Vp[q] = make_float4(v[2 * q].x, v[2 * q].y, v[2 * q + 1].x, v[2 * q + 1].y);
}

// ---------------- fused edge kernel (512 edges/block) -----------------------
// Direct-to-fragment: lane (ln,half) of wave w builds A fragments for edges
// e0=64w+ln and e1=e0+32 straight from global (channels [8h,8h+8) and
// [16+8h,+8)); B fragment from the precomputed 2KB WbtG table. No staging
// LDS, single barrier. LDS = m matrix only: 8256 dw = 33 KB.
__global__ __launch_bounds__(EBS, 6) void edge_seg_kernel(
    const unsigned* __restrict__ Ubf, const float4* __restrict__ V,
    const int* __restrict__ row_ptr, const int* __restrict__ cnt,
    const int2* __restrict__ sedge, const unsigned* __restrict__ WbtG,
    const float* __restrict__ bb, unsigned* __restrict__ agg, int E) {
    __shared__ __align__(16) unsigned lds[8256];

    const int tid = threadIdx.x;
    const int k0 = blockIdx.x * EBS;
    const int blockEnd = min(k0 + EBS, E);

    const int l = tid & 63;
    const int w = tid >> 6;  // 0..7, wave w covers edges 64w..64w+63
    const int half = l >> 5;
    const int ln = l & 31;

    const int e0 = min(k0 + 64 * w + ln, E - 1);
    const int e1 = min(e0 + 32, E - 1);

    // B fragments: precomputed per-lane packed bf16 (L1-hot, 2 loads)
    const uint4 bu0 = *reinterpret_cast<const uint4*>(WbtG + l * 8);
    const uint4 bu1 = *reinterpret_cast<const uint4*>(WbtG + l * 8 + 4);
    const float bbn = bb[ln];

    // A fragments directly from global: Ubf dword j = channels (2j,2j+1);
    // V float4 q = channels 4q..4q+3. Same cvt2/fmax chain as before ->
    // bit-identical numerics.
    uint4 au00, au01, au10, au11;
    {
        const int2 ed = sedge[e0];
        const uint4* Up = reinterpret_cast<const uint4*>(Ubf + (size_t)ed.x * 16);
        const float4* Vp = V + (size_t)ed.y * 8;
        const uint4 ua = Up[half];      // ch 8h..8h+7
        const uint4 ub = Up[2 + half];  // ch 16+8h..16+8h+7
        au00 = mk_frag(ua, Vp[2 * half], Vp[2 * half + 1]);
        au01 = mk_frag(ub, Vp[4 + 2 * half], Vp[5 + 2 * half]);
    }
    {
        const int2 ed = sedge[e1];
        const uint4* Up = reinterpret_cast<const uint4*>(Ubf + (size_t)ed.x * 16);
        const float4* Vp = V + (size_t)ed.y * 8;
        const uint4 ua = Up[half];
        const uint4 ub = Up[2 + half];
        au10 = mk_frag(ua, Vp[2 * half], Vp[2 * half + 1]);
        au11 = mk_frag(ub, Vp[4 + 2 * half], Vp[5 + 2 * half]);
    }

    // bias folded into C init (column n = ln gets bb[n])
    f32x16 c0, c1;
#pragma unroll
    for (int i = 0; i < 16; ++i) {
        c0[i] = bbn;
        c1[i] = bbn;
    }
    c0 = __builtin_amdgcn_mfma_f32_32x32x16_bf16(__builtin_bit_cast(bf16x8, au00),
                                                 __builtin_bit_cast(bf16x8, bu0), c0, 0, 0, 0);
    c0 = __builtin_amdgcn_mfma_f32_32x32x16_bf16(__builtin_bit_cast(bf16x8, au01),
                                                 __builtin_bit_cast(bf16x8, bu1), c0, 0, 0, 0);
    c1 = __builtin_amdgcn_mfma_f32_32x32x16_bf16(__builtin_bit_cast(bf16x8, au10),
                                                 __builtin_bit_cast(bf16x8, bu0), c1, 0, 0, 0);
    c1 = __builtin_amdgcn_mfma_f32_32x32x16_bf16(__builtin_bit_cast(bf16x8, au11),
                                                 __builtin_bit_cast(bf16x8, bu1), c1, 0, 0, 0);

    // write m as bf16 EDGE-pairs: C rows rr, rr+1 are consecutive edges.
    // smb[ch][ep] stride 258 -> bank (2*ch + ep) % 32: 2-way max (free).
    // Waves write disjoint pair ranges [32w, 32w+32) -> no barrier needed
    // before this write; one barrier after, before the segmented max.
#pragma unroll
    for (int k2 = 0; k2 < 8; ++k2) {
        const int rr = 2 * k2;
        const int er = 64 * w + (rr & 3) + 8 * (rr >> 2) + 4 * half;  // even
        lds[ln * 258 + (er >> 1)] = cvt2(c0[rr], c0[rr + 1]);
        lds[ln * 258 + (er >> 1) + 16] = cvt2(c1[rr], c1[rr + 1]);
    }
    __syncthreads();

    // phase 2: segmented max; pair-reads along edges with odd-end fixups
    const int d0 = sedge[k0].y;
    const int d1 = sedge[blockEnd - 1].y;
    const int nPairs = (d1 - d0 + 1) * 32;
    for (int idx = tid; idx < nPairs; idx += EBS) {
        const int c = idx & 31;
        const int n = d0 + (idx >> 5);
        const int rs = row_ptr[n];
        const int re = rs + cnt[n];
        const int s0 = max(rs, k0) - k0;
        const int s1 = min(re, blockEnd) - k0;
        if (s0 >= s1) continue;
        const unsigned* smc = &lds[c * 258];
        v2f m0 = {-INFINITY, -INFINITY};
        v2f m1 = m0;
        int e = s0;
        if (e & 1) {
            const unsigned u = smc[e >> 1];
            m0.x = fmaxf(m0.x, bfhi(u));
            ++e;
        }
        for (; e + 4 <= s1; e += 4) {
            const unsigned ua = smc[e >> 1];
            const unsigned ub = smc[(e >> 1) + 1];
            const v2f a = {bflo(ua), bfhi(ua)};
            const v2f b = {bflo(ub), bfhi(ub)};
            m0 = __builtin_elementwise_max(m0, a);
            m1 = __builtin_elementwise_max(m1, b);
        }
        if (e + 2 <= s1) {
            const unsigned u = smc[e >> 1];
            const v2f a = {bflo(u), bfhi(u)};
            m0 = __builtin_elementwise_max(m0, a);
            e += 2;
        }
        if (e < s1) m0.x = fmaxf(m0.x, bflo(smc[e >> 1]));
        const v2f mm = __builtin_elementwise_max(m0, m1);
        const float v = fmaxf(mm.x, mm.y);
        unsigned* p = &agg[(size_t)n * 32 + c];
        const unsigned enc = ordenc(v);
        if (rs >= k0 && re <= blockEnd)
            *p = enc;
        else
            atomicMax(p, enc);
    }
}

extern "C" void kernel_launch(void* const* d_in, const int* in_sizes, int n_in,
                              void* d_out, int out_size, void* d_ws, size_t ws_size,
                              hipStream_t stream) {
    const float* pos = (const float*)d_in[0];
    const int* ei = (const int*)d_in[1];
    const float* W1 = (const float*)d_in[3];
    const float* b1 = (const float*)d_in[4];
    const float* W2 = (const float*)d_in[5];
    const float* b2 = (const float*)d_in[6];
    const float* W3 = (const float*)d_in[7];
    const float* b3 = (const float*)d_in[8];
    const float* W4 = (const float*)d_in[9];
    const float* b4 = (const float*)d_in[10];

    const int E = in_sizes[1] / 2;
    const int N = in_sizes[0] / 3;
    const int n32 = N * 32;
    const int NPAD = ((N + BS - 1) / BS) * BS;
    const int EB2 = (E + EBS - 1) / EBS;
    const int NR = (N + 127) / 128;         // ranges of 128 dsts
    const int NRP = ((NR + 15) / 16) * 16;  // padded (<= 1024)
    const int NB1 = (E + K1_EDGES - 1) / K1_EDGES;
    const int BH = NB1 * NRP;

    int* cnt = (int*)d_ws;                    // NPAD
    int* row_ptr = cnt + NPAD;                // NPAD
    int* blockHist = row_ptr + NPAD;          // BH
    int* off = blockHist + BH;                // BH
    int* total = off + BH;                    // NRP
    int* rangeBase = total + NRP;             // NRP
    int2* sedge = (int2*)(rangeBase + NRP);   // E (offsets all mult-of-4 ints)
    int2* sedgeB = sedge + E;                 // E (dedicated)
    unsigned* aggA = (unsigned*)(sedgeB + E);         // n32
    unsigned* Ubf = aggA + n32;                       // NPAD*16 (bf16-packed U)
    float* Vbuf = (float*)(Ubf + (size_t)NPAD * 16);  // n32
    unsigned* WbtG = (unsigned*)(Vbuf + n32);         // 1024 dw (2 layers x 512)
    unsigned* aggB = (unsigned*)d_out;

    const int gridN32 = (n32 + BS - 1) / BS;
    const int NBn = (N + BS - 1) / BS;

    // fused: hist | prep1 | agg-init | Wbt pack (mutually independent)
    setup_kernel<<<NB1 + NBn + gridN32 + 1, BS, 0, stream>>>(
        ei, E, NRP, blockHist, pos, W1, b1, Ubf, Vbuf, N, aggA, aggB, n32, NB1, NBn,
        gridN32, W2, W4, WbtG);
    off_scan_kernel<<<(NRP * 64 + 511) / 512, 512, 0, stream>>>(blockHist, NB1, NRP, off,
                                                                total);
    range_scan_kernel<<<1, 1024, 0, stream>>>(total, NRP, rangeBase);
    bucket_scatter_kernel<<<NB1, BS, 0, stream>>>(ei, E, NRP, off, rangeBase, sedgeB);
    bucket_sort_kernel<<<NR, BS, 0, stream>>>(sedgeB, rangeBase, total, N, sedge, row_ptr, cnt);

    // --- layer 1 ---
    edge_seg_kernel<<<EB2, EBS, 0, stream>>>(Ubf, (const float4*)Vbuf, row_ptr, cnt, sedge,
                                             WbtG, b2, aggA, E);
    // --- layer 2 ---
    prep2_kernel<<<NBn, BS, 0, stream>>>(pos, aggA, W3, b3, Ubf, Vbuf, N);
    edge_seg_kernel<<<EB2, EBS, 0, stream>>>(Ubf, (const float4*)Vbuf, row_ptr, cnt, sedge,
                                             WbtG + 512, b4, aggB, E);
    finalize_kernel<<<gridN32, BS, 0, stream>>>(aggB, n32);
}